// Round 2
// baseline (405.667 us; speedup 1.0000x reference)
//
#include <hip/hip_runtime.h>
#include <hip/hip_bf16.h>

#define DIMK 512
#define NROWS 131072
#define BM 128
#define BN 128
#define BK 64

typedef __bf16 bf16x8 __attribute__((ext_vector_type(8)));
typedef float f32x4 __attribute__((ext_vector_type(4)));

// bf16 [n][k] transposed weight, written by wprep_kernel each launch.
__device__ __attribute__((aligned(16))) unsigned short g_Wt[DIMK * DIMK];

static __device__ __forceinline__ unsigned short f2bf(float f) {
    unsigned u = __builtin_bit_cast(unsigned, f);
    u += 0x7FFFu + ((u >> 16) & 1u);   // round-to-nearest-even
    return (unsigned short)(u >> 16);
}

static __device__ __forceinline__ unsigned pack2(float a, float b) {
    return (unsigned)f2bf(a) | ((unsigned)f2bf(b) << 16);
}

// Classify mask dtype at runtime. Reads first 32768 words = 131072 bytes,
// in-bounds for uint8(131072B)/int32(512KB)/int64(1MB) interpretations.
//   mode 0: byte bool   (some word not in {0,1})
//   mode 1: int32 0/1   (all words in {0,1}, ~50% nonzero)
//   mode 2: int64 0/1   (all words in {0,1}, ~25% nonzero: odd words all 0)
__global__ void mask_detect(const unsigned int* __restrict__ m, int* __restrict__ mode) {
    __shared__ int s_bad;
    __shared__ int s_cnt;
    const int t = threadIdx.x;  // 256
    if (t == 0) { s_bad = 0; s_cnt = 0; }
    __syncthreads();
    int bad = 0, cnt = 0;
    for (int i = t; i < 32768; i += 256) {
        unsigned w = m[i];
        bad |= (w > 1u) ? 1 : 0;
        cnt += (w != 0u) ? 1 : 0;
    }
    atomicOr(&s_bad, bad);
    atomicAdd(&s_cnt, cnt);
    __syncthreads();
    if (t == 0) {
        int md;
        if (s_bad) md = 0;
        else if (s_cnt > 12288) md = 1;
        else md = 2;
        *mode = md;
    }
}

// Transpose + convert: W[k][n] fp32 -> g_Wt[n][k] bf16. 64x64 tiles, 64 blocks.
__global__ void wprep_kernel(const float* __restrict__ W) {
    __shared__ float tile[64][65];
    const int bk = blockIdx.x & 7;   // k-tile
    const int bn = blockIdx.x >> 3;  // n-tile
    const int t = threadIdx.x;       // 256
    const int rl = t >> 2;           // 0..63
    const int ch = t & 3;            // 0..3, 16 floats each

    const float* src = W + (bk * 64 + rl) * DIMK + bn * 64 + ch * 16;
    float4 v[4];
#pragma unroll
    for (int i = 0; i < 4; i++) v[i] = reinterpret_cast<const float4*>(src)[i];
#pragma unroll
    for (int i = 0; i < 4; i++) {
        tile[rl][ch * 16 + i * 4 + 0] = v[i].x;
        tile[rl][ch * 16 + i * 4 + 1] = v[i].y;
        tile[rl][ch * 16 + i * 4 + 2] = v[i].z;
        tile[rl][ch * 16 + i * 4 + 3] = v[i].w;
    }
    __syncthreads();

    unsigned outw[8];
#pragma unroll
    for (int i = 0; i < 8; i++)
        outw[i] = pack2(tile[ch * 16 + 2 * i][rl], tile[ch * 16 + 2 * i + 1][rl]);

    unsigned short* dst = g_Wt + (bn * 64 + rl) * DIMK + bk * 64 + ch * 16;
    uint4* d4 = reinterpret_cast<uint4*>(dst);
    d4[0] = make_uint4(outw[0], outw[1], outw[2], outw[3]);
    d4[1] = make_uint4(outw[4], outw[5], outw[6], outw[7]);
}

// GEMM: out[r] = mask[r] ? bf16gemm(x,W)[r] : x[r]
// 128x128 tile, BK=64, 256 threads = 4 waves (2x2), each wave 64x64.
__global__ __launch_bounds__(256, 2)
void gemm_kernel(const float* __restrict__ X, const void* __restrict__ maskp,
                 const int* __restrict__ modep, float* __restrict__ out) {
    __shared__ __attribute__((aligned(16))) unsigned short Abuf[2][BM * BK];

    const int md = *modep;

    // XCD-bijective swizzle: 4096 blocks, col-tile fastest so the 4 column
    // tiles of one A row-panel are consecutive logical ids on one XCD.
    const int lid = ((blockIdx.x & 7) << 9) + (blockIdx.x >> 3);
    const int tm = lid >> 2;
    const int tn = lid & 3;
    const long row0 = (long)tm * BM;
    const int col0 = tn * BN;

    const int t = threadIdx.x;
    const int lane = t & 63;
    const int wid = t >> 6;
    const int wr = wid >> 1;
    const int wc = wid & 1;
    const int l15 = lane & 15;
    const int lhi = lane >> 4;

    // staging decomposition: chunk sc covers k elems [sc*8, sc*8+8)
    const int sc = t & 7;
    const int sr = t >> 3;  // 0..31, rows sr, sr+32, sr+64, sr+96

    f32x4 acc[4][4] = {};

    const float* Xb = X + row0 * DIMK;

    float4 ga[4][2];
#pragma unroll
    for (int i = 0; i < 4; i++) {
        const float* p = Xb + (sr + i * 32) * DIMK + sc * 8;
        ga[i][0] = reinterpret_cast<const float4*>(p)[0];
        ga[i][1] = reinterpret_cast<const float4*>(p)[1];
    }

    int cur = 0;

    auto stage_write = [&](int buf) {
#pragma unroll
        for (int i = 0; i < 4; i++) {
            const int r = sr + i * 32;
            uint4 val = make_uint4(pack2(ga[i][0].x, ga[i][0].y),
                                   pack2(ga[i][0].z, ga[i][0].w),
                                   pack2(ga[i][1].x, ga[i][1].y),
                                   pack2(ga[i][1].z, ga[i][1].w));
            const int byteoff = r * 128 + ((sc * 16) ^ ((r & 7) << 4));
            *reinterpret_cast<uint4*>(reinterpret_cast<char*>(Abuf[buf]) + byteoff) = val;
        }
    };
    stage_write(0);

#pragma unroll 1
    for (int kt = 0; kt < 8; kt++) {
        __syncthreads();
        const int k0 = kt * BK;
        if (kt < 7) {  // issue next tile's global loads early (hide under MFMA)
#pragma unroll
            for (int i = 0; i < 4; i++) {
                const float* p = Xb + (sr + i * 32) * DIMK + (k0 + BK) + sc * 8;
                ga[i][0] = reinterpret_cast<const float4*>(p)[0];
                ga[i][1] = reinterpret_cast<const float4*>(p)[1];
            }
        }
        const char* Ab = reinterpret_cast<const char*>(Abuf[cur]);
#pragma unroll
        for (int s = 0; s < 2; s++) {
            bf16x8 bfr[4], afr[4];
#pragma unroll
            for (int n = 0; n < 4; n++) {
                const unsigned short* bp = g_Wt +
                    (long)(col0 + wc * 64 + n * 16 + l15) * DIMK + k0 + s * 32 + lhi * 8;
                bfr[n] = *reinterpret_cast<const bf16x8*>(bp);
            }
#pragma unroll
            for (int m = 0; m < 4; m++) {
                const int row_l = wr * 64 + m * 16 + l15;
                const int kb = (s * 64 + lhi * 16) ^ ((row_l & 7) << 4);
                afr[m] = *reinterpret_cast<const bf16x8*>(Ab + row_l * 128 + kb);
            }
#pragma unroll
            for (int m = 0; m < 4; m++)
#pragma unroll
                for (int n = 0; n < 4; n++)
                    acc[m][n] = __builtin_amdgcn_mfma_f32_16x16x32_bf16(
                        afr[m], bfr[n], acc[m][n], 0, 0, 0);
        }
        if (kt < 7) stage_write(cur ^ 1);
        cur ^= 1;
    }

    // epilogue: C/D layout col = lane&15, row = (lane>>4)*4 + reg
    const int nb = col0 + wc * 64;
    const long rb = row0 + wr * 64;
#pragma unroll
    for (int m = 0; m < 4; m++) {
#pragma unroll
        for (int j = 0; j < 4; j++) {
            const long rg = rb + m * 16 + lhi * 4 + j;
            bool msk;
            if (md == 0)      msk = ((const unsigned char*)maskp)[rg] != 0;
            else if (md == 1) msk = ((const int*)maskp)[rg] != 0;
            else              msk = ((const unsigned int*)maskp)[2 * rg] != 0;
            float* orow = out + rg * DIMK + nb;
            const float* xrow = X + rg * DIMK + nb;
#pragma unroll
            for (int n = 0; n < 4; n++) {
                float v = acc[m][n][j];
                if (!msk) v = xrow[n * 16 + l15];
                orow[n * 16 + l15] = v;
            }
        }
    }
}

extern "C" void kernel_launch(void* const* d_in, const int* in_sizes, int n_in,
                              void* d_out, int out_size, void* d_ws, size_t ws_size,
                              hipStream_t stream) {
    const float* X = (const float*)d_in[0];
    const void* mask = d_in[1];
    const float* W = (const float*)d_in[2];
    float* out = (float*)d_out;
    int* mode = (int*)d_ws;

    hipLaunchKernelGGL(mask_detect, dim3(1), dim3(256), 0, stream,
                       (const unsigned int*)mask, mode);
    hipLaunchKernelGGL(wprep_kernel, dim3(64), dim3(256), 0, stream, W);
    hipLaunchKernelGGL(gemm_kernel, dim3(NROWS / BM * (DIMK / BN)), dim3(256), 0, stream,
                       X, mask, mode, out);
}